// Round 2
// baseline (539.761 us; speedup 1.0000x reference)
//
#include <hip/hip_runtime.h>

// Shapes (fixed by the problem): B=256, T=5, S=64, F=256, H=4, Fh=64, N=H*B=1024
// x:[B,T,S,F] f32. Output f32 same shape.

// ---------------- prior[t,s,c] = 1/(sqrt(2pi)*sigma) * exp(-dis^2/(2 sigma^2)) ----
__global__ __launch_bounds__(256) void prior_kernel(const float* __restrict__ dis,
                                                    const float* __restrict__ sigma,
                                                    float* __restrict__ prior) {
  int i = blockIdx.x * 256 + threadIdx.x;
  if (i >= 5 * 64 * 64) return;
  int ts = i >> 6;               // t*64+s
  float sg = sigma[ts];
  float d = dis[i];
  prior[i] = 0.3989422804014327f / sg * __expf(-d * d / (2.f * sg * sg));
}

// ---------------- k[b,s,f] = sum_t u[t] * x[b,t,s,f] -----------------------------
__global__ __launch_bounds__(256) void k_kernel(const float* __restrict__ x,
                                                const float* __restrict__ u,
                                                float* __restrict__ kout) {
  int i = blockIdx.x * 256 + threadIdx.x;      // float4 id, total 1048576
  size_t j = (size_t)i * 4;
  int b = (int)(j >> 14);                      // / 16384  (S*F)
  int off = (int)(j & 16383);
  const float* xp = x + (size_t)b * 81920 + off;
  float u0 = u[0], u1 = u[1], u2 = u[2], u3 = u[3], u4 = u[4];
  float4 a0 = *(const float4*)(xp);
  float4 a1 = *(const float4*)(xp + 16384);
  float4 a2 = *(const float4*)(xp + 32768);
  float4 a3 = *(const float4*)(xp + 49152);
  float4 a4 = *(const float4*)(xp + 65536);
  float4 r;
  r.x = u0 * a0.x + u1 * a1.x + u2 * a2.x + u3 * a3.x + u4 * a4.x;
  r.y = u0 * a0.y + u1 * a1.y + u2 * a2.y + u3 * a3.y + u4 * a4.y;
  r.z = u0 * a0.z + u1 * a1.z + u2 * a2.z + u3 * a3.z + u4 * a4.z;
  r.w = u0 * a0.w + u1 * a1.w + u2 * a2.w + u3 * a3.w + u4 * a4.w;
  *(float4*)(kout + j) = r;
}

// ---------------- C[M,256] = (A .* scale) @ W[256,256] ---------------------------
// scale==nullptr -> no scaling. scale[m*4 + k/64] applied to A[m,k] (column-quarter).
// M = 81920 fixed. Tile 128x128, BK=16, 256 threads, 8x8 micro-tile.
__global__ __launch_bounds__(256) void gemm_f32(const float* __restrict__ A,
                                                const float* __restrict__ W,
                                                float* __restrict__ C,
                                                const float* __restrict__ scale) {
  __shared__ float As[16][132];
  __shared__ float Bs[16][132];
  const int tid = threadIdx.x;
  const int tx = tid & 15, ty = tid >> 4;
  const int row0 = blockIdx.x * 128;
  const int col0 = blockIdx.y * 128;
  float acc[8][8] = {};
  for (int k0 = 0; k0 < 256; k0 += 16) {
    // stage A: 128 rows x 16 k
    for (int l = 0; l < 2; ++l) {
      int fid = tid + l * 256;           // 0..511
      int r = fid >> 2, kq = (fid & 3) * 4;
      float4 a = *(const float4*)(A + (size_t)(row0 + r) * 256 + k0 + kq);
      if (scale) {
        float s = scale[(size_t)(row0 + r) * 4 + ((k0 + kq) >> 6)];
        a.x *= s; a.y *= s; a.z *= s; a.w *= s;
      }
      As[kq + 0][r] = a.x; As[kq + 1][r] = a.y; As[kq + 2][r] = a.z; As[kq + 3][r] = a.w;
    }
    // stage B: 16 k x 128 n
    for (int l = 0; l < 2; ++l) {
      int fid = tid + l * 256;
      int kk = fid >> 5, nq = (fid & 31) * 4;
      *(float4*)&Bs[kk][nq] = *(const float4*)(W + (size_t)(k0 + kk) * 256 + col0 + nq);
    }
    __syncthreads();
    for (int kk = 0; kk < 16; ++kk) {
      float a[8], b[8];
      *(float4*)&a[0] = *(float4*)&As[kk][ty * 8];
      *(float4*)&a[4] = *(float4*)&As[kk][ty * 8 + 4];
      *(float4*)&b[0] = *(float4*)&Bs[kk][tx * 8];
      *(float4*)&b[4] = *(float4*)&Bs[kk][tx * 8 + 4];
      for (int i = 0; i < 8; ++i)
        for (int j = 0; j < 8; ++j) acc[i][j] += a[i] * b[j];
    }
    __syncthreads();
  }
  for (int i = 0; i < 8; ++i) {
    float4 c0 = {acc[i][0], acc[i][1], acc[i][2], acc[i][3]};
    float4 c1 = {acc[i][4], acc[i][5], acc[i][6], acc[i][7]};
    float* cp = C + (size_t)(row0 + ty * 8 + i) * 256 + col0 + tx * 8;
    *(float4*)(cp) = c0;
    *(float4*)(cp + 4) = c1;
  }
}

// ---------------- score + reduce over s --------------------------------------------
// ssum[n,t,c] = sum_s (sigmoid(qk[n,t,s,c]/8) - bias[n%256,t,s,c]) * prior[t,s,c]
// q flat [N=1024][T=5][S=64][Fh=64]; kr[n,fh,c] = kbuf[(n>>2)*16384 + c*256 + (n&3)*64 + fh]
__global__ __launch_bounds__(256) void score_kernel(const float* __restrict__ q,
                                                    const float* __restrict__ kbuf,
                                                    const float* __restrict__ bias,
                                                    const float* __restrict__ prior,
                                                    float* __restrict__ ssum) {
  __shared__ float qs[64][68];
  __shared__ float ks[64][68];
  __shared__ float red[16][68];
  const int n = blockIdx.x;          // 0..1023
  const int tid = threadIdx.x;
  const int nb = n & 255;
  const float* kb = kbuf + ((size_t)(n >> 2)) * 16384 + (n & 3) * 64;
  for (int l = 0; l < 4; ++l) {
    int fid = tid + l * 256;         // 0..1023
    int c = fid >> 4, f4 = (fid & 15) * 4;
    *(float4*)&ks[c][f4] = *(const float4*)(kb + c * 256 + f4);
  }
  const int cid = tid & 15, sid = tid >> 4;
  const int c4 = cid * 4, s4 = sid * 4;
  for (int t = 0; t < 5; ++t) {
    __syncthreads();                 // protect qs/red from previous iteration readers
    const float* qt = q + (size_t)n * 20480 + t * 4096;
    for (int l = 0; l < 4; ++l) {
      int fid = tid + l * 256;
      int s = fid >> 4, f4 = (fid & 15) * 4;
      *(float4*)&qs[s][f4] = *(const float4*)(qt + s * 64 + f4);
    }
    __syncthreads();
    float acc[4][4] = {};
    for (int f4 = 0; f4 < 64; f4 += 4) {
      float a[4][4], b[4][4];
      for (int i = 0; i < 4; ++i) *(float4*)a[i] = *(float4*)&qs[s4 + i][f4];
      for (int j = 0; j < 4; ++j) *(float4*)b[j] = *(float4*)&ks[c4 + j][f4];
      for (int i = 0; i < 4; ++i)
        for (int j = 0; j < 4; ++j) {
          acc[i][j] += a[i][0] * b[j][0] + a[i][1] * b[j][1] +
                       a[i][2] * b[j][2] + a[i][3] * b[j][3];
        }
    }
    const float* bp = bias + (size_t)nb * 20480 + t * 4096;
    const float* pp = prior + t * 4096;
    float psum[4] = {0.f, 0.f, 0.f, 0.f};
    for (int i = 0; i < 4; ++i) {
      float4 bv = *(const float4*)(bp + (s4 + i) * 64 + c4);
      float4 pv = *(const float4*)(pp + (s4 + i) * 64 + c4);
      float bb[4] = {bv.x, bv.y, bv.z, bv.w};
      float pr[4] = {pv.x, pv.y, pv.z, pv.w};
      for (int j = 0; j < 4; ++j) {
        float sc = 1.f / (1.f + __expf(-acc[i][j] * 0.125f));
        psum[j] += (sc - bb[j]) * pr[j];
      }
    }
    for (int j = 0; j < 4; ++j) red[sid][c4 + j] = psum[j];
    __syncthreads();
    if (tid < 64) {
      float s = 0.f;
      for (int i = 0; i < 16; ++i) s += red[i][tid];
      ssum[(size_t)n * 320 + t * 64 + tid] = s;
    }
  }
}

// ---------------- SE reductions: avg & max over o[b,t,:,:] (16384 contiguous) ------
__global__ __launch_bounds__(256) void se_reduce(const float* __restrict__ o,
                                                 float* __restrict__ ravg,
                                                 float* __restrict__ rmax) {
  int bt = blockIdx.x;               // 0..1279
  const float* p = o + (size_t)bt * 16384;
  int tid = threadIdx.x;
  float sum = 0.f, mx = -3.4e38f;
  for (int l = 0; l < 16; ++l) {
    float4 v = *(const float4*)(p + l * 1024 + tid * 4);
    sum += v.x + v.y + v.z + v.w;
    mx = fmaxf(mx, fmaxf(fmaxf(v.x, v.y), fmaxf(v.z, v.w)));
  }
  for (int off = 32; off; off >>= 1) {
    sum += __shfl_down(sum, off);
    mx = fmaxf(mx, __shfl_down(mx, off));
  }
  __shared__ float wsum[4], wmax[4];
  if ((tid & 63) == 0) { wsum[tid >> 6] = sum; wmax[tid >> 6] = mx; }
  __syncthreads();
  if (tid == 0) {
    float s = wsum[0] + wsum[1] + wsum[2] + wsum[3];
    float m = fmaxf(fmaxf(wmax[0], wmax[1]), fmaxf(wmax[2], wmax[3]));
    ravg[bt] = s * (1.f / 16384.f);
    rmax[bt] = m;
  }
}

// ---------------- SE MLP: se[b,t] --------------------------------------------------
__global__ __launch_bounds__(256) void se_mlp(const float* __restrict__ ravg,
                                              const float* __restrict__ rmax,
                                              const float* __restrict__ fc1w,
                                              const float* __restrict__ fc1b,
                                              const float* __restrict__ fc2w,
                                              const float* __restrict__ fc2b,
                                              const float* __restrict__ bili,
                                              float* __restrict__ se) {
  int b = threadIdx.x;               // one block of 256
  float avg[5], mx[5];
  for (int t = 0; t < 5; ++t) { avg[t] = ravg[b * 5 + t]; mx[t] = rmax[b * 5 + t]; }
  float w = bili[0];
  float h[25], s1[5], s2[5];
  for (int j = 0; j < 25; ++j) {
    float a = fc1b[j];
    for (int t = 0; t < 5; ++t) a += avg[t] * fc1w[t * 25 + j];
    h[j] = fmaxf(a, 0.f);
  }
  for (int t = 0; t < 5; ++t) {
    float a = fc2b[t];
    for (int j = 0; j < 25; ++j) a += h[j] * fc2w[j * 5 + t];
    s1[t] = 1.f / (1.f + __expf(-a));
  }
  for (int j = 0; j < 25; ++j) {
    float a = fc1b[j];
    for (int t = 0; t < 5; ++t) a += mx[t] * fc1w[t * 25 + j];
    h[j] = fmaxf(a, 0.f);
  }
  for (int t = 0; t < 5; ++t) {
    float a = fc2b[t];
    for (int j = 0; j < 25; ++j) a += h[j] * fc2w[j * 5 + t];
    s2[t] = 1.f / (1.f + __expf(-a));
  }
  for (int t = 0; t < 5; ++t) se[b * 5 + t] = (1.f - w) * s1[t] + w * s2[t];
}

// ---------------- final: out = o*se[b,t] + x (in place on d_out) -------------------
__global__ __launch_bounds__(256) void final_kernel(const float* __restrict__ x,
                                                    const float* __restrict__ se,
                                                    float* __restrict__ out) {
  int i = blockIdx.x * 256 + threadIdx.x;      // float4 id, 5242880 total
  size_t j = (size_t)i * 4;
  int bt = (int)(j >> 14);
  float s = se[bt];
  float4 o = *(float4*)(out + j);
  float4 xv = *(const float4*)(x + j);
  float4 r = {o.x * s + xv.x, o.y * s + xv.y, o.z * s + xv.z, o.w * s + xv.w};
  *(float4*)(out + j) = r;
}

extern "C" void kernel_launch(void* const* d_in, const int* in_sizes, int n_in,
                              void* d_out, int out_size, void* d_ws, size_t ws_size,
                              hipStream_t stream) {
  const float* x     = (const float*)d_in[0];
  const float* bias  = (const float*)d_in[1];
  const float* Wq    = (const float*)d_in[2];
  const float* Wv    = (const float*)d_in[3];
  const float* Wo    = (const float*)d_in[4];
  const float* u_t   = (const float*)d_in[5];
  const float* dis   = (const float*)d_in[6];
  const float* sigma = (const float*)d_in[7];
  const float* fc1w  = (const float*)d_in[8];
  const float* fc1b  = (const float*)d_in[9];
  const float* fc2w  = (const float*)d_in[10];
  const float* fc2b  = (const float*)d_in[11];
  const float* bili  = (const float*)d_in[12];
  float* out = (float*)d_out;

  // workspace layout (floats): total ~25.52M floats = ~102 MB
  float* ws    = (float*)d_ws;
  float* kbuf  = ws;                       // 4,194,304
  float* qv    = kbuf + 4194304;           // 20,971,520  (q, then reused for v)
  float* ssum  = qv + 20971520;            // 327,680
  float* prior = ssum + 327680;            // 20,480
  float* ravg  = prior + 20480;            // 1,280
  float* rmax  = ravg + 1280;              // 1,280
  float* se    = rmax + 1280;              // 1,280

  prior_kernel<<<80, 256, 0, stream>>>(dis, sigma, prior);
  k_kernel<<<4096, 256, 0, stream>>>(x, u_t, kbuf);
  // q = x @ Wq
  gemm_f32<<<dim3(640, 2), 256, 0, stream>>>(x, Wq, qv, nullptr);
  score_kernel<<<1024, 256, 0, stream>>>(qv, kbuf, bias, prior, ssum);
  // v = x @ Wv (overwrites q)
  gemm_f32<<<dim3(640, 2), 256, 0, stream>>>(x, Wv, qv, nullptr);
  // o = (v .* ssum) @ Wo  -> d_out
  gemm_f32<<<dim3(640, 2), 256, 0, stream>>>(qv, Wo, out, ssum);
  se_reduce<<<1280, 256, 0, stream>>>(out, ravg, rmax);
  se_mlp<<<1, 256, 0, stream>>>(ravg, rmax, fc1w, fc1b, fc2w, fc2b, bili, se);
  final_kernel<<<20480, 256, 0, stream>>>(x, se, out);
}

// Round 3
// 213.098 us; speedup vs baseline: 2.5329x; 2.5329x over previous
//
#include <hip/hip_runtime.h>

// B=256, T=5, S=64, F=256, H=4, Fh=64, N=H*B=1024, M=81920 rows of [.,256]

typedef unsigned short ushort_t;
typedef __attribute__((ext_vector_type(8))) short bf16x8;
typedef __attribute__((ext_vector_type(4))) float f32x4;

__device__ inline ushort_t f2bf(float f) {            // RNE f32 -> bf16
  unsigned u = __float_as_uint(f);
  return (ushort_t)((u + 0x7FFFu + ((u >> 16) & 1u)) >> 16);
}
__device__ inline float bflo(unsigned u) { return __uint_as_float(u << 16); }
__device__ inline float bfhi(unsigned u) { return __uint_as_float(u & 0xFFFF0000u); }

// ---------------- prior[t,s,c] ----------------------------------------------------
__global__ __launch_bounds__(256) void prior_kernel(const float* __restrict__ dis,
                                                    const float* __restrict__ sigma,
                                                    float* __restrict__ prior) {
  int i = blockIdx.x * 256 + threadIdx.x;
  if (i >= 5 * 64 * 64) return;
  int ts = i >> 6;
  float sg = sigma[ts];
  float d = dis[i];
  prior[i] = 0.3989422804014327f / sg * __expf(-d * d / (2.f * sg * sg));
}

// ---------------- k[b,s,f] = sum_t u[t]*x[b,t,s,f] -> bf16 ------------------------
__global__ __launch_bounds__(256) void k_kernel(const float* __restrict__ x,
                                                const float* __restrict__ u,
                                                ushort_t* __restrict__ kout) {
  int i = blockIdx.x * 256 + threadIdx.x;      // float4 id, total 1048576
  size_t j = (size_t)i * 4;
  int b = (int)(j >> 14);
  int off = (int)(j & 16383);
  const float* xp = x + (size_t)b * 81920 + off;
  float u0 = u[0], u1 = u[1], u2 = u[2], u3 = u[3], u4 = u[4];
  float4 a0 = *(const float4*)(xp);
  float4 a1 = *(const float4*)(xp + 16384);
  float4 a2 = *(const float4*)(xp + 32768);
  float4 a3 = *(const float4*)(xp + 49152);
  float4 a4 = *(const float4*)(xp + 65536);
  float4 r;
  r.x = u0 * a0.x + u1 * a1.x + u2 * a2.x + u3 * a3.x + u4 * a4.x;
  r.y = u0 * a0.y + u1 * a1.y + u2 * a2.y + u3 * a3.y + u4 * a4.y;
  r.z = u0 * a0.z + u1 * a1.z + u2 * a2.z + u3 * a3.z + u4 * a4.z;
  r.w = u0 * a0.w + u1 * a1.w + u2 * a2.w + u3 * a3.w + u4 * a4.w;
  ushort4 h = {f2bf(r.x), f2bf(r.y), f2bf(r.z), f2bf(r.w)};
  *(ushort4*)(kout + j) = h;
}

// ---------------- W^T convert: Wt[mat][n][k] = bf16(W[k][n]) ----------------------
__global__ __launch_bounds__(256) void convert_w(const float* __restrict__ Wq,
                                                 const float* __restrict__ Wv,
                                                 const float* __restrict__ Wo,
                                                 ushort_t* __restrict__ Wt) {
  int id = blockIdx.x * 256 + threadIdx.x;     // 196608
  if (id >= 196608) return;
  int mat = id >> 16, rem = id & 65535;
  int n = rem >> 8, k = rem & 255;
  const float* W = mat == 0 ? Wq : (mat == 1 ? Wv : Wo);
  Wt[id] = f2bf(W[k * 256 + n]);
}

// ---------------- MFMA GEMM: C_bf16[M,256] = A @ Wt^T -----------------------------
// A: f32 (convert on stage) or bf16. SCALE: acc *= ssum[row*4 + col/64] (v-GEMM).
// SEEPI: block-local SE avg/max over its 2 complete (b,t) row-groups (o-GEMM).
// BM=128, BN=256, BK=64, 512 threads = 8 waves (2 x 4), 16x16x32 bf16 MFMA.
// LDS tiles XOR-swizzled in 16B chunks: chunk c of row r stored at c^(r&7).
template<int ABF16, int SCALE, int SEEPI>
__global__ __launch_bounds__(512, 4) void gemm_mfma(
    const void* __restrict__ Aip, const ushort_t* __restrict__ Wt,
    ushort_t* __restrict__ C, const float* __restrict__ ssum,
    float* __restrict__ ravg, float* __restrict__ rmax) {
  __shared__ __align__(16) ushort_t As_[128 * 64];
  __shared__ __align__(16) ushort_t Bs_[256 * 64];
  __shared__ float redS[8], redM[8];
  const int tid = threadIdx.x;
  const int lane = tid & 63;
  const int w = tid >> 6, wr = w >> 2, wc = w & 3;
  const int row0 = blockIdx.x * 128;
  const int cl = lane & 15, ql = lane >> 4, l7 = lane & 7;

  f32x4 acc[4][4];
#pragma unroll
  for (int i = 0; i < 4; ++i)
#pragma unroll
    for (int j = 0; j < 4; ++j) acc[i][j] = (f32x4){0.f, 0.f, 0.f, 0.f};

  for (int t = 0; t < 4; ++t) {
    const int k0 = t * 64;
    if (t) __syncthreads();
    if (ABF16) {
      const ushort_t* A = (const ushort_t*)Aip;
#pragma unroll
      for (int l = 0; l < 2; ++l) {
        int i = l * 512 + tid;                 // 1024 16B chunks
        int r = i >> 3, c = i & 7;
        uint4 v = *(const uint4*)(A + (size_t)(row0 + r) * 256 + k0 + c * 8);
        *(uint4*)&As_[r * 64 + ((c ^ (r & 7)) * 8)] = v;
      }
    } else {
      const float* A = (const float*)Aip;
#pragma unroll
      for (int l = 0; l < 4; ++l) {
        int i = l * 512 + tid;                 // 2048 f32x4 chunks
        int r = i >> 4, c4 = i & 15;
        float4 v = *(const float4*)(A + (size_t)(row0 + r) * 256 + k0 + c4 * 4);
        ushort4 h = {f2bf(v.x), f2bf(v.y), f2bf(v.z), f2bf(v.w)};
        *(ushort4*)&As_[r * 64 + (((c4 >> 1) ^ (r & 7)) * 8) + (c4 & 1) * 4] = h;
      }
    }
#pragma unroll
    for (int l = 0; l < 4; ++l) {              // B: 2048 16B chunks
      int i = l * 512 + tid;
      int n = i >> 3, c = i & 7;
      uint4 v = *(const uint4*)(Wt + (size_t)n * 256 + k0 + c * 8);
      *(uint4*)&Bs_[n * 64 + ((c ^ (n & 7)) * 8)] = v;
    }
    __syncthreads();
#pragma unroll
    for (int kk = 0; kk < 2; ++kk) {
      const int offk = (((kk << 2) | ql) ^ l7) * 8;
      bf16x8 bfr[4], afr[4];
#pragma unroll
      for (int ni = 0; ni < 4; ++ni)
        bfr[ni] = *(const bf16x8*)&Bs_[(wc * 64 + ni * 16 + cl) * 64 + offk];
#pragma unroll
      for (int mi = 0; mi < 4; ++mi)
        afr[mi] = *(const bf16x8*)&As_[(wr * 64 + mi * 16 + cl) * 64 + offk];
#pragma unroll
      for (int mi = 0; mi < 4; ++mi)
#pragma unroll
        for (int ni = 0; ni < 4; ++ni)
          acc[mi][ni] = __builtin_amdgcn_mfma_f32_16x16x32_bf16(afr[mi], bfr[ni], acc[mi][ni], 0, 0, 0);
    }
  }
  // epilogue: D row = wr*64+mi*16+ql*4+r, col = wc*64+ni*16+cl
  float lsum = 0.f, lmax = -3.4e38f;
#pragma unroll
  for (int mi = 0; mi < 4; ++mi) {
    float sc[4];
    if (SCALE) {
#pragma unroll
      for (int r = 0; r < 4; ++r)
        sc[r] = ssum[(size_t)(row0 + wr * 64 + mi * 16 + ql * 4 + r) * 4 + wc];
    }
#pragma unroll
    for (int ni = 0; ni < 4; ++ni) {
      int col = wc * 64 + ni * 16 + cl;
      f32x4 v = acc[mi][ni];
#pragma unroll
      for (int r = 0; r < 4; ++r) {
        int row = row0 + wr * 64 + mi * 16 + ql * 4 + r;
        float f = v[r];
        if (SCALE) f *= sc[r];
        C[(size_t)row * 256 + col] = f2bf(f);
        if (SEEPI) { lsum += f; lmax = fmaxf(lmax, f); }
      }
    }
  }
  if (SEEPI) {
#pragma unroll
    for (int off = 32; off; off >>= 1) {
      lsum += __shfl_xor(lsum, off);
      lmax = fmaxf(lmax, __shfl_xor(lmax, off));
    }
    if (lane == 0) { redS[w] = lsum; redM[w] = lmax; }
    __syncthreads();
    if (tid < 2) {                             // group bt = row0/64 + tid (tid==wr)
      float s = redS[tid * 4] + redS[tid * 4 + 1] + redS[tid * 4 + 2] + redS[tid * 4 + 3];
      float m = fmaxf(fmaxf(redM[tid * 4], redM[tid * 4 + 1]),
                      fmaxf(redM[tid * 4 + 2], redM[tid * 4 + 3]));
      ravg[blockIdx.x * 2 + tid] = s * (1.f / 16384.f);
      rmax[blockIdx.x * 2 + tid] = m;
    }
  }
}

// ---------------- score + reduce over s (bf16 q,k inputs) -------------------------
__global__ __launch_bounds__(256) void score_kernel(const ushort_t* __restrict__ q,
                                                    const ushort_t* __restrict__ kbuf,
                                                    const float* __restrict__ bias,
                                                    const float* __restrict__ prior,
                                                    float* __restrict__ ssum) {
  __shared__ float qs[64][68];
  __shared__ float ks[64][68];
  __shared__ float red[16][68];
  const int n = blockIdx.x;
  const int tid = threadIdx.x;
  const int nb = n & 255;
  const ushort_t* kb = kbuf + (size_t)(n >> 2) * 16384 + (n & 3) * 64;
  for (int l = 0; l < 2; ++l) {
    int fid = tid + l * 256;                   // 512 chunks of 8 bf16
    int c = fid >> 3, f8 = (fid & 7) * 8;
    uint4 u = *(const uint4*)(kb + c * 256 + f8);
    float* d = &ks[c][f8];
    d[0] = bflo(u.x); d[1] = bfhi(u.x); d[2] = bflo(u.y); d[3] = bfhi(u.y);
    d[4] = bflo(u.z); d[5] = bfhi(u.z); d[6] = bflo(u.w); d[7] = bfhi(u.w);
  }
  const int cid = tid & 15, sid = tid >> 4;
  const int c4 = cid * 4, s4 = sid * 4;
  for (int t = 0; t < 5; ++t) {
    __syncthreads();
    const ushort_t* qt = q + (size_t)n * 20480 + t * 4096;
    for (int l = 0; l < 2; ++l) {
      int fid = tid + l * 256;
      int s = fid >> 3, f8 = (fid & 7) * 8;
      uint4 u = *(const uint4*)(qt + s * 64 + f8);
      float* d = &qs[s][f8];
      d[0] = bflo(u.x); d[1] = bfhi(u.x); d[2] = bflo(u.y); d[3] = bfhi(u.y);
      d[4] = bflo(u.z); d[5] = bfhi(u.z); d[6] = bflo(u.w); d[7] = bfhi(u.w);
    }
    __syncthreads();
    float acc[4][4] = {};
    for (int f4 = 0; f4 < 64; f4 += 4) {
      float a[4][4], b[4][4];
      for (int i = 0; i < 4; ++i) *(float4*)a[i] = *(float4*)&qs[s4 + i][f4];
      for (int j = 0; j < 4; ++j) *(float4*)b[j] = *(float4*)&ks[c4 + j][f4];
      for (int i = 0; i < 4; ++i)
        for (int j = 0; j < 4; ++j)
          acc[i][j] += a[i][0] * b[j][0] + a[i][1] * b[j][1] +
                       a[i][2] * b[j][2] + a[i][3] * b[j][3];
    }
    const float* bp = bias + (size_t)nb * 20480 + t * 4096;
    const float* pp = prior + t * 4096;
    float psum[4] = {0.f, 0.f, 0.f, 0.f};
    for (int i = 0; i < 4; ++i) {
      float4 bv = *(const float4*)(bp + (s4 + i) * 64 + c4);
      float4 pv = *(const float4*)(pp + (s4 + i) * 64 + c4);
      float bb[4] = {bv.x, bv.y, bv.z, bv.w};
      float pr[4] = {pv.x, pv.y, pv.z, pv.w};
      for (int j = 0; j < 4; ++j) {
        float sc = 1.f / (1.f + __expf(-acc[i][j] * 0.125f));
        psum[j] += (sc - bb[j]) * pr[j];
      }
    }
    for (int j = 0; j < 4; ++j) red[sid][c4 + j] = psum[j];
    __syncthreads();
    if (tid < 64) {
      float s = 0.f;
      for (int i = 0; i < 16; ++i) s += red[i][tid];
      ssum[(size_t)n * 320 + t * 64 + tid] = s;
    }
  }
}

// ---------------- SE MLP ----------------------------------------------------------
__global__ __launch_bounds__(256) void se_mlp(const float* __restrict__ ravg,
                                              const float* __restrict__ rmax,
                                              const float* __restrict__ fc1w,
                                              const float* __restrict__ fc1b,
                                              const float* __restrict__ fc2w,
                                              const float* __restrict__ fc2b,
                                              const float* __restrict__ bili,
                                              float* __restrict__ se) {
  int b = threadIdx.x;
  float avg[5], mx[5];
  for (int t = 0; t < 5; ++t) { avg[t] = ravg[b * 5 + t]; mx[t] = rmax[b * 5 + t]; }
  float w = bili[0];
  float h[25], s1[5], s2[5];
  for (int j = 0; j < 25; ++j) {
    float a = fc1b[j];
    for (int t = 0; t < 5; ++t) a += avg[t] * fc1w[t * 25 + j];
    h[j] = fmaxf(a, 0.f);
  }
  for (int t = 0; t < 5; ++t) {
    float a = fc2b[t];
    for (int j = 0; j < 25; ++j) a += h[j] * fc2w[j * 5 + t];
    s1[t] = 1.f / (1.f + __expf(-a));
  }
  for (int j = 0; j < 25; ++j) {
    float a = fc1b[j];
    for (int t = 0; t < 5; ++t) a += mx[t] * fc1w[t * 25 + j];
    h[j] = fmaxf(a, 0.f);
  }
  for (int t = 0; t < 5; ++t) {
    float a = fc2b[t];
    for (int j = 0; j < 25; ++j) a += h[j] * fc2w[j * 5 + t];
    s2[t] = 1.f / (1.f + __expf(-a));
  }
  for (int t = 0; t < 5; ++t) se[b * 5 + t] = (1.f - w) * s1[t] + w * s2[t];
}

// ---------------- final: out = bf16(o)*se[b,t] + x --------------------------------
__global__ __launch_bounds__(256) void final_kernel(const float* __restrict__ x,
                                                    const float* __restrict__ se,
                                                    const ushort_t* __restrict__ ob,
                                                    float* __restrict__ out) {
  int i = blockIdx.x * 256 + threadIdx.x;      // float4 id, 5242880
  size_t j = (size_t)i * 4;
  int bt = (int)(j >> 14);
  float s = se[bt];
  uint2 u = *(const uint2*)(ob + j);
  float4 xv = *(const float4*)(x + j);
  float4 r = {bflo(u.x) * s + xv.x, bfhi(u.x) * s + xv.y,
              bflo(u.y) * s + xv.z, bfhi(u.y) * s + xv.w};
  *(float4*)(out + j) = r;
}

extern "C" void kernel_launch(void* const* d_in, const int* in_sizes, int n_in,
                              void* d_out, int out_size, void* d_ws, size_t ws_size,
                              hipStream_t stream) {
  const float* x     = (const float*)d_in[0];
  const float* bias  = (const float*)d_in[1];
  const float* Wq    = (const float*)d_in[2];
  const float* Wv    = (const float*)d_in[3];
  const float* Wo    = (const float*)d_in[4];
  const float* u_t   = (const float*)d_in[5];
  const float* dis   = (const float*)d_in[6];
  const float* sigma = (const float*)d_in[7];
  const float* fc1w  = (const float*)d_in[8];
  const float* fc1b  = (const float*)d_in[9];
  const float* fc2w  = (const float*)d_in[10];
  const float* fc2b  = (const float*)d_in[11];
  const float* bili  = (const float*)d_in[12];
  float* out = (float*)d_out;

  // workspace layout (bytes), total ~94.5 MB
  char* wsb = (char*)d_ws;
  ushort_t* qvb  = (ushort_t*)wsb;             wsb += 41943040;  // q, then v*ssum
  ushort_t* ob   = (ushort_t*)wsb;             wsb += 41943040;  // o bf16
  ushort_t* kb   = (ushort_t*)wsb;             wsb += 8388608;   // k bf16 [B,S,F]
  ushort_t* Wt   = (ushort_t*)wsb;             wsb += 393216;    // 3 x W^T bf16
  float*    ssum = (float*)wsb;                wsb += 1310720;
  float*    prior= (float*)wsb;                wsb += 81920;
  float*    ravg = (float*)wsb;                wsb += 5120;
  float*    rmax = (float*)wsb;                wsb += 5120;
  float*    se   = (float*)wsb;                wsb += 5120;

  convert_w<<<768, 256, 0, stream>>>(Wq, Wv, Wo, Wt);
  k_kernel<<<4096, 256, 0, stream>>>(x, u_t, kb);
  prior_kernel<<<80, 256, 0, stream>>>(dis, sigma, prior);
  // q = bf16(x) @ Wq
  gemm_mfma<0, 0, 0><<<640, 512, 0, stream>>>(x, Wt, qvb, nullptr, nullptr, nullptr);
  score_kernel<<<1024, 256, 0, stream>>>(qvb, kb, bias, prior, ssum);
  // v = bf16(x) @ Wv, scaled by ssum in epilogue
  gemm_mfma<0, 1, 0><<<640, 512, 0, stream>>>(x, Wt + 65536, qvb, ssum, nullptr, nullptr);
  // o = (v.*s) @ Wo, with fused SE avg/max reduction
  gemm_mfma<1, 0, 1><<<640, 512, 0, stream>>>(qvb, Wt + 131072, ob, nullptr, ravg, rmax);
  se_mlp<<<1, 256, 0, stream>>>(ravg, rmax, fc1w, fc1b, fc2w, fc2b, bili, se);
  final_kernel<<<20480, 256, 0, stream>>>(x, se, ob, out);
}

// Round 4
// 172.306 us; speedup vs baseline: 3.1326x; 1.2367x over previous
//
#include <hip/hip_runtime.h>

// B=256, T=5, S=64, F=256, H=4, Fh=64, N=H*B=1024, M=81920 rows of [.,256]

typedef unsigned short ushort_t;
typedef __attribute__((ext_vector_type(8))) short bf16x8;
typedef __attribute__((ext_vector_type(4))) float f32x4;

__device__ inline ushort_t f2bf(float f) {            // RNE f32 -> bf16
  unsigned u = __float_as_uint(f);
  return (ushort_t)((u + 0x7FFFu + ((u >> 16) & 1u)) >> 16);
}
__device__ inline float bflo(unsigned u) { return __uint_as_float(u << 16); }
__device__ inline float bfhi(unsigned u) { return __uint_as_float(u & 0xFFFF0000u); }

// ---------------- prior[t,s,c] ----------------------------------------------------
__global__ __launch_bounds__(256) void prior_kernel(const float* __restrict__ dis,
                                                    const float* __restrict__ sigma,
                                                    float* __restrict__ prior) {
  int i = blockIdx.x * 256 + threadIdx.x;
  if (i >= 5 * 64 * 64) return;
  int ts = i >> 6;
  float sg = sigma[ts];
  float d = dis[i];
  prior[i] = 0.3989422804014327f / sg * __expf(-d * d / (2.f * sg * sg));
}

// ---------------- bps[nb,t,c] = sum_s bias[nb,t,s,c]*prior[t,s,c] -----------------
__global__ __launch_bounds__(256) void bias_prior_sum(const float* __restrict__ bias,
                                                      const float* __restrict__ prior,
                                                      float* __restrict__ bps) {
  int blk = blockIdx.x;              // nb*5 + t, 1280 blocks
  int t = blk % 5, tid = threadIdx.x;
  const float* bp = bias + (size_t)blk * 4096;
  const float* pp = prior + t * 4096;
  int c = tid & 63, sg = tid >> 6;
  float sum = 0.f;
  for (int s = sg * 16; s < sg * 16 + 16; ++s)
    sum += bp[s * 64 + c] * pp[s * 64 + c];
  __shared__ float red[4][64];
  red[sg][c] = sum;
  __syncthreads();
  if (tid < 64)
    bps[(size_t)blk * 64 + tid] = red[0][tid] + red[1][tid] + red[2][tid] + red[3][tid];
}

// ---------------- k[b,s,f] = sum_t u[t]*x -> bf16;  xb = bf16(x) ------------------
__global__ __launch_bounds__(256) void k_kernel(const float* __restrict__ x,
                                                const float* __restrict__ u,
                                                ushort_t* __restrict__ kout,
                                                ushort_t* __restrict__ xb) {
  int i = blockIdx.x * 256 + threadIdx.x;      // float4 id, total 1048576
  size_t j = (size_t)i * 4;
  int b = (int)(j >> 14);
  int off = (int)(j & 16383);
  const float* xp = x + (size_t)b * 81920 + off;
  ushort_t* xq = xb + (size_t)b * 81920 + off;
  float u0 = u[0], u1 = u[1], u2 = u[2], u3 = u[3], u4 = u[4];
  float4 a0 = *(const float4*)(xp);
  float4 a1 = *(const float4*)(xp + 16384);
  float4 a2 = *(const float4*)(xp + 32768);
  float4 a3 = *(const float4*)(xp + 49152);
  float4 a4 = *(const float4*)(xp + 65536);
  ushort4 h0 = {f2bf(a0.x), f2bf(a0.y), f2bf(a0.z), f2bf(a0.w)};
  ushort4 h1 = {f2bf(a1.x), f2bf(a1.y), f2bf(a1.z), f2bf(a1.w)};
  ushort4 h2 = {f2bf(a2.x), f2bf(a2.y), f2bf(a2.z), f2bf(a2.w)};
  ushort4 h3 = {f2bf(a3.x), f2bf(a3.y), f2bf(a3.z), f2bf(a3.w)};
  ushort4 h4 = {f2bf(a4.x), f2bf(a4.y), f2bf(a4.z), f2bf(a4.w)};
  *(ushort4*)(xq) = h0;
  *(ushort4*)(xq + 16384) = h1;
  *(ushort4*)(xq + 32768) = h2;
  *(ushort4*)(xq + 49152) = h3;
  *(ushort4*)(xq + 65536) = h4;
  float4 r;
  r.x = u0 * a0.x + u1 * a1.x + u2 * a2.x + u3 * a3.x + u4 * a4.x;
  r.y = u0 * a0.y + u1 * a1.y + u2 * a2.y + u3 * a3.y + u4 * a4.y;
  r.z = u0 * a0.z + u1 * a1.z + u2 * a2.z + u3 * a3.z + u4 * a4.z;
  r.w = u0 * a0.w + u1 * a1.w + u2 * a2.w + u3 * a3.w + u4 * a4.w;
  ushort4 h = {f2bf(r.x), f2bf(r.y), f2bf(r.z), f2bf(r.w)};
  *(ushort4*)(kout + j) = h;
}

// ---------------- W^T convert: Wt[mat][n][k] = bf16(W[k][n]) ----------------------
__global__ __launch_bounds__(256) void convert_w(const float* __restrict__ Wq,
                                                 const float* __restrict__ Wv,
                                                 const float* __restrict__ Wo,
                                                 ushort_t* __restrict__ Wt) {
  int id = blockIdx.x * 256 + threadIdx.x;     // 196608
  if (id >= 196608) return;
  int mat = id >> 16, rem = id & 65535;
  int n = rem >> 8, k = rem & 255;
  const float* W = mat == 0 ? Wq : (mat == 1 ? Wv : Wo);
  Wt[id] = f2bf(W[k * 256 + n]);
}

// ---------------- MFMA GEMM: C_bf16[M,256] = A_bf16 @ Wt^T ------------------------
// SCALE: acc *= ssum[row*4 + col/64] (v-GEMM). SEEPI: fused SE avg/max (o-GEMM).
// BM=128, BN=256, BK=64, 512 threads = 8 waves (2 x 4), 16x16x32 bf16 MFMA.
// LDS tiles XOR-swizzled in 16B chunks: chunk c of row r stored at c^(r&7).
template<int SCALE, int SEEPI>
__global__ __launch_bounds__(512, 4) void gemm_mfma(
    const ushort_t* __restrict__ A, const ushort_t* __restrict__ Wt,
    ushort_t* __restrict__ C, const float* __restrict__ ssum,
    float* __restrict__ ravg, float* __restrict__ rmax) {
  __shared__ __align__(16) ushort_t As_[128 * 64];
  __shared__ __align__(16) ushort_t Bs_[256 * 64];
  __shared__ float redS[8], redM[8];
  const int tid = threadIdx.x;
  const int lane = tid & 63;
  const int w = tid >> 6, wr = w >> 2, wc = w & 3;
  const int row0 = blockIdx.x * 128;
  const int cl = lane & 15, ql = lane >> 4, l7 = lane & 7;

  f32x4 acc[4][4];
#pragma unroll
  for (int i = 0; i < 4; ++i)
#pragma unroll
    for (int j = 0; j < 4; ++j) acc[i][j] = (f32x4){0.f, 0.f, 0.f, 0.f};

  for (int t = 0; t < 4; ++t) {
    const int k0 = t * 64;
    if (t) __syncthreads();
#pragma unroll
    for (int l = 0; l < 2; ++l) {              // A: 1024 16B chunks
      int i = l * 512 + tid;
      int r = i >> 3, c = i & 7;
      uint4 v = *(const uint4*)(A + (size_t)(row0 + r) * 256 + k0 + c * 8);
      *(uint4*)&As_[r * 64 + ((c ^ (r & 7)) * 8)] = v;
    }
#pragma unroll
    for (int l = 0; l < 4; ++l) {              // B: 2048 16B chunks
      int i = l * 512 + tid;
      int n = i >> 3, c = i & 7;
      uint4 v = *(const uint4*)(Wt + (size_t)n * 256 + k0 + c * 8);
      *(uint4*)&Bs_[n * 64 + ((c ^ (n & 7)) * 8)] = v;
    }
    __syncthreads();
#pragma unroll
    for (int kk = 0; kk < 2; ++kk) {
      const int offk = (((kk << 2) | ql) ^ l7) * 8;
      bf16x8 bfr[4], afr[4];
#pragma unroll
      for (int ni = 0; ni < 4; ++ni)
        bfr[ni] = *(const bf16x8*)&Bs_[(wc * 64 + ni * 16 + cl) * 64 + offk];
#pragma unroll
      for (int mi = 0; mi < 4; ++mi)
        afr[mi] = *(const bf16x8*)&As_[(wr * 64 + mi * 16 + cl) * 64 + offk];
#pragma unroll
      for (int mi = 0; mi < 4; ++mi)
#pragma unroll
        for (int ni = 0; ni < 4; ++ni)
          acc[mi][ni] = __builtin_amdgcn_mfma_f32_16x16x32_bf16(afr[mi], bfr[ni], acc[mi][ni], 0, 0, 0);
    }
  }
  // epilogue: D row = wr*64+mi*16+ql*4+r, col = wc*64+ni*16+cl
  float lsum = 0.f, lmax = -3.4e38f;
#pragma unroll
  for (int mi = 0; mi < 4; ++mi) {
    float sc[4];
    if (SCALE) {
#pragma unroll
      for (int r = 0; r < 4; ++r)
        sc[r] = ssum[(size_t)(row0 + wr * 64 + mi * 16 + ql * 4 + r) * 4 + wc];
    }
#pragma unroll
    for (int ni = 0; ni < 4; ++ni) {
      int col = wc * 64 + ni * 16 + cl;
      f32x4 v = acc[mi][ni];
#pragma unroll
      for (int r = 0; r < 4; ++r) {
        int row = row0 + wr * 64 + mi * 16 + ql * 4 + r;
        float f = v[r];
        if (SCALE) f *= sc[r];
        C[(size_t)row * 256 + col] = f2bf(f);
        if (SEEPI) { lsum += f; lmax = fmaxf(lmax, f); }
      }
    }
  }
  if (SEEPI) {
#pragma unroll
    for (int off = 32; off; off >>= 1) {
      lsum += __shfl_xor(lsum, off);
      lmax = fmaxf(lmax, __shfl_xor(lmax, off));
    }
    if (lane == 0) { redS[w] = lsum; redM[w] = lmax; }
    __syncthreads();
    if (tid < 2) {
      float s = redS[tid * 4] + redS[tid * 4 + 1] + redS[tid * 4 + 2] + redS[tid * 4 + 3];
      float m = fmaxf(fmaxf(redM[tid * 4], redM[tid * 4 + 1]),
                      fmaxf(redM[tid * 4 + 2], redM[tid * 4 + 3]));
      ravg[blockIdx.x * 2 + tid] = s * (1.f / 16384.f);
      rmax[blockIdx.x * 2 + tid] = m;
    }
  }
}

// ---------------- score via MFMA ---------------------------------------------------
// ssum[n,t,c] = sum_s sigmoid(qk/8)*prior[t,s,c] - bps[n%256,t,c]
// Block = one n, 4 waves; wave w owns col-strip c in [w*16, w*16+16).
// A-frag: lane holds q[row=si*16+(l&15)][k=(l>>4)*8..+8]; B-frag from k-slice
// (element (c,fh) at kb + c*256 + fh): lane holds col c=(l&15), k-chunk (l>>4)*8.
__global__ __launch_bounds__(256) void score_mfma(const ushort_t* __restrict__ q,
                                                  const ushort_t* __restrict__ kbuf,
                                                  const float* __restrict__ prior,
                                                  const float* __restrict__ bps,
                                                  float* __restrict__ ssum) {
  const int n = blockIdx.x;
  const int tid = threadIdx.x;
  const int lane = tid & 63;
  const int w = tid >> 6;
  const int cl = lane & 15, ql = lane >> 4;
  const int nb = n & 255;
  const int c = w * 16 + cl;
  const ushort_t* kb = kbuf + (size_t)(n >> 2) * 16384 + (n & 3) * 64;
  bf16x8 kfr0 = *(const bf16x8*)(kb + c * 256 + ql * 8);
  bf16x8 kfr1 = *(const bf16x8*)(kb + c * 256 + ql * 8 + 32);
  for (int t = 0; t < 5; ++t) {
    const ushort_t* qt = q + (size_t)n * 20480 + t * 4096;
    f32x4 acc[4];
#pragma unroll
    for (int si = 0; si < 4; ++si) {
      bf16x8 a0 = *(const bf16x8*)(qt + (si * 16 + cl) * 64 + ql * 8);
      bf16x8 a1 = *(const bf16x8*)(qt + (si * 16 + cl) * 64 + ql * 8 + 32);
      f32x4 z = (f32x4){0.f, 0.f, 0.f, 0.f};
      z = __builtin_amdgcn_mfma_f32_16x16x32_bf16(a0, kfr0, z, 0, 0, 0);
      z = __builtin_amdgcn_mfma_f32_16x16x32_bf16(a1, kfr1, z, 0, 0, 0);
      acc[si] = z;
    }
    const float* pp = prior + t * 4096;
    float colsum = 0.f;
#pragma unroll
    for (int si = 0; si < 4; ++si) {
#pragma unroll
      for (int r = 0; r < 4; ++r) {
        int s = si * 16 + ql * 4 + r;
        float sg = 1.f / (1.f + __expf(-acc[si][r] * 0.125f));
        colsum += sg * pp[s * 64 + c];
      }
    }
    colsum += __shfl_xor(colsum, 16);
    colsum += __shfl_xor(colsum, 32);
    if (ql == 0)
      ssum[(size_t)n * 320 + t * 64 + c] = colsum - bps[((size_t)nb * 5 + t) * 64 + c];
  }
}

// ---------------- SE MLP ----------------------------------------------------------
__global__ __launch_bounds__(256) void se_mlp(const float* __restrict__ ravg,
                                              const float* __restrict__ rmax,
                                              const float* __restrict__ fc1w,
                                              const float* __restrict__ fc1b,
                                              const float* __restrict__ fc2w,
                                              const float* __restrict__ fc2b,
                                              const float* __restrict__ bili,
                                              float* __restrict__ se) {
  int b = threadIdx.x;
  float avg[5], mx[5];
  for (int t = 0; t < 5; ++t) { avg[t] = ravg[b * 5 + t]; mx[t] = rmax[b * 5 + t]; }
  float w = bili[0];
  float h[25], s1[5], s2[5];
  for (int j = 0; j < 25; ++j) {
    float a = fc1b[j];
    for (int t = 0; t < 5; ++t) a += avg[t] * fc1w[t * 25 + j];
    h[j] = fmaxf(a, 0.f);
  }
  for (int t = 0; t < 5; ++t) {
    float a = fc2b[t];
    for (int j = 0; j < 25; ++j) a += h[j] * fc2w[j * 5 + t];
    s1[t] = 1.f / (1.f + __expf(-a));
  }
  for (int j = 0; j < 25; ++j) {
    float a = fc1b[j];
    for (int t = 0; t < 5; ++t) a += mx[t] * fc1w[t * 25 + j];
    h[j] = fmaxf(a, 0.f);
  }
  for (int t = 0; t < 5; ++t) {
    float a = fc2b[t];
    for (int j = 0; j < 25; ++j) a += h[j] * fc2w[j * 5 + t];
    s2[t] = 1.f / (1.f + __expf(-a));
  }
  for (int t = 0; t < 5; ++t) se[b * 5 + t] = (1.f - w) * s1[t] + w * s2[t];
}

// ---------------- final: out = bf16(o)*se[b,t] + x --------------------------------
__global__ __launch_bounds__(256) void final_kernel(const float* __restrict__ x,
                                                    const float* __restrict__ se,
                                                    const ushort_t* __restrict__ ob,
                                                    float* __restrict__ out) {
  int i = blockIdx.x * 256 + threadIdx.x;      // float4 id, 5242880
  size_t j = (size_t)i * 4;
  int bt = (int)(j >> 14);
  float s = se[bt];
  uint2 u = *(const uint2*)(ob + j);
  float4 xv = *(const float4*)(x + j);
  float4 r = {bflo(u.x) * s + xv.x, bfhi(u.x) * s + xv.y,
              bflo(u.y) * s + xv.z, bfhi(u.y) * s + xv.w};
  *(float4*)(out + j) = r;
}

extern "C" void kernel_launch(void* const* d_in, const int* in_sizes, int n_in,
                              void* d_out, int out_size, void* d_ws, size_t ws_size,
                              hipStream_t stream) {
  const float* x     = (const float*)d_in[0];
  const float* bias  = (const float*)d_in[1];
  const float* Wq    = (const float*)d_in[2];
  const float* Wv    = (const float*)d_in[3];
  const float* Wo    = (const float*)d_in[4];
  const float* u_t   = (const float*)d_in[5];
  const float* dis   = (const float*)d_in[6];
  const float* sigma = (const float*)d_in[7];
  const float* fc1w  = (const float*)d_in[8];
  const float* fc1b  = (const float*)d_in[9];
  const float* fc2w  = (const float*)d_in[10];
  const float* fc2b  = (const float*)d_in[11];
  const float* bili  = (const float*)d_in[12];
  float* out = (float*)d_out;

  // workspace layout (bytes), ~95 MB. xb and ob SHARE a buffer:
  // xb lifetime: k_kernel -> v-GEMM; ob lifetime: o-GEMM -> final (disjoint).
  char* wsb = (char*)d_ws;
  ushort_t* qvb  = (ushort_t*)wsb;             wsb += 41943040;  // q, then v*ssum
  ushort_t* xob  = (ushort_t*)wsb;             wsb += 41943040;  // xb / ob
  ushort_t* kb   = (ushort_t*)wsb;             wsb += 8388608;   // k bf16 [B,S,F]
  ushort_t* Wt   = (ushort_t*)wsb;             wsb += 393216;    // 3 x W^T bf16
  float*    ssum = (float*)wsb;                wsb += 1310720;
  float*    prior= (float*)wsb;                wsb += 81920;
  float*    bps  = (float*)wsb;                wsb += 327680;
  float*    ravg = (float*)wsb;                wsb += 5120;
  float*    rmax = (float*)wsb;                wsb += 5120;
  float*    se   = (float*)wsb;                wsb += 5120;

  convert_w<<<768, 256, 0, stream>>>(Wq, Wv, Wo, Wt);
  prior_kernel<<<80, 256, 0, stream>>>(dis, sigma, prior);
  bias_prior_sum<<<1280, 256, 0, stream>>>(bias, prior, bps);
  k_kernel<<<4096, 256, 0, stream>>>(x, u_t, kb, xob);
  // q = xb @ Wq
  gemm_mfma<0, 0><<<640, 512, 0, stream>>>(xob, Wt, qvb, nullptr, nullptr, nullptr);
  score_mfma<<<1024, 256, 0, stream>>>(qvb, kb, prior, bps, ssum);
  // v = xb @ Wv, scaled by ssum in epilogue (overwrites qvb)
  gemm_mfma<1, 0><<<640, 512, 0, stream>>>(xob, Wt + 65536, qvb, ssum, nullptr, nullptr);
  // o = (v.*s) @ Wo -> ob (xb dead), fused SE avg/max
  gemm_mfma<0, 1><<<640, 512, 0, stream>>>(qvb, Wt + 131072, xob, nullptr, ravg, rmax);
  se_mlp<<<1, 256, 0, stream>>>(ravg, rmax, fc1w, fc1b, fc2w, fc2b, bili, se);
  final_kernel<<<20480, 256, 0, stream>>>(x, se, xob, out);
}